// Round 1
// baseline (689.464 us; speedup 1.0000x reference)
//
#include <hip/hip_runtime.h>
#include <hip/hip_bf16.h>

#define B_ 128
#define L_ 1024
#define T_ 512   // L/2 tokens per parity
#define D_ 768
#define DT_ 513  // output tokens per batch
#define TAU 5e-5f

typedef __attribute__((ext_vector_type(8))) short bf16x8;
typedef __attribute__((ext_vector_type(4))) float f32x4;

__device__ __forceinline__ unsigned short f2bf_rne(float x){
    unsigned u = __float_as_uint(x);
    unsigned r = (u + 0x7FFFu + ((u >> 16) & 1u)) >> 16;
    return (unsigned short)r;
}
__device__ __forceinline__ float bf2f(unsigned short h){
    return __uint_as_float(((unsigned)h) << 16);
}

// ---------------- norms: fp64-accurate 1/|x| and |x|^2 ----------------
__global__ __launch_bounds__(256) void norms_k(const float* __restrict__ hs,
                                               float* __restrict__ rnorm,
                                               double* __restrict__ nsq){
    int wave = threadIdx.x >> 6, lane = threadIdx.x & 63;
    long row = (long)blockIdx.x * 4 + wave;           // < B*L
    const float* p = hs + row * D_;
    double s = 0.0;
    #pragma unroll
    for (int dd = 0; dd < 12; ++dd){
        float v = p[dd * 64 + lane];
        s += (double)v * (double)v;
    }
    #pragma unroll
    for (int off = 32; off; off >>= 1) s += __shfl_xor(s, off);
    if (lane == 0){
        nsq[row] = s;
        rnorm[row] = (float)(1.0 / sqrt(s));
    }
}

// ---------------- scores: split-bf16 3-pass MFMA, fused row max/argmax ----------------
// grid: b(128) x it(8: 64 even rows) x jt(4: 128 odd rows). K = 768 in steps of 32.
__global__ __launch_bounds__(256) void scores_k(const float* __restrict__ hs,
                                                const float* __restrict__ rnorm,
                                                float* __restrict__ pmax1,
                                                int*   __restrict__ pj1,
                                                float* __restrict__ pmax2){
    __shared__ __align__(16) char smem[36096];
    unsigned short* Ahi = (unsigned short*)smem;              // 64x40 shorts
    unsigned short* Alo = (unsigned short*)(smem + 5120);
    unsigned short* Bhi = (unsigned short*)(smem + 10240);    // 128x40 shorts
    unsigned short* Blo = (unsigned short*)(smem + 20480);
    float* S   = (float*)smem;                                 // 64x129 f32 (reuses staging)
    float* cm1 = (float*)(smem + 33024);
    float* cm2 = (float*)(smem + 34048);
    int*   cj1 = (int*)  (smem + 35072);

    int bid = blockIdx.x;
    int b = bid >> 5, rem = bid & 31, it = rem >> 2, jt = rem & 3;
    int tid = threadIdx.x;

    int rowA = tid >> 2, kcA = (tid & 3) * 8;    // 64 rows x 32 k
    int rowB = tid >> 1, kcB = (tid & 1) * 16;   // 128 rows x 32 k
    long baseA = ((long)b * L_ + 2 * (it * 64 + rowA)) * D_ + kcA;
    long baseB = ((long)b * L_ + 2 * (jt * 128 + rowB) + 1) * D_ + kcB;
    float rnA = rnorm[b * L_ + 2 * (it * 64 + rowA)];
    float rnB = rnorm[b * L_ + 2 * (jt * 128 + rowB) + 1];

    int wv = tid >> 6, lane = tid & 63;
    int l15 = lane & 15, l4 = lane >> 4;

    f32x4 acc[4][2];
    #pragma unroll
    for (int i = 0; i < 4; ++i)
        #pragma unroll
        for (int j = 0; j < 2; ++j) acc[i][j] = (f32x4){0.f, 0.f, 0.f, 0.f};

    for (int k0 = 0; k0 < D_; k0 += 32){
        { // stage A (8 floats -> hi/lo bf16)
            const float4* g = (const float4*)(hs + baseA + k0);
            float4 x0 = g[0], x1 = g[1];
            float v[8] = {x0.x,x0.y,x0.z,x0.w,x1.x,x1.y,x1.z,x1.w};
            #pragma unroll
            for (int e = 0; e < 8; ++e){
                float a = v[e] * rnA;
                unsigned short h = f2bf_rne(a);
                unsigned short l = f2bf_rne(a - bf2f(h));
                Ahi[rowA * 40 + kcA + e] = h;
                Alo[rowA * 40 + kcA + e] = l;
            }
        }
        { // stage B (16 floats)
            const float4* g = (const float4*)(hs + baseB + k0);
            #pragma unroll
            for (int q = 0; q < 4; ++q){
                float4 x = g[q];
                float v[4] = {x.x,x.y,x.z,x.w};
                #pragma unroll
                for (int e = 0; e < 4; ++e){
                    float a = v[e] * rnB;
                    unsigned short h = f2bf_rne(a);
                    unsigned short l = f2bf_rne(a - bf2f(h));
                    Bhi[rowB * 40 + kcB + q * 4 + e] = h;
                    Blo[rowB * 40 + kcB + q * 4 + e] = l;
                }
            }
        }
        __syncthreads();
        bf16x8 ah[4], al[4], bh[2], bl[2];
        #pragma unroll
        for (int ib = 0; ib < 4; ++ib){
            int r = ib * 16 + l15;
            ah[ib] = *(const bf16x8*)&Ahi[r * 40 + l4 * 8];
            al[ib] = *(const bf16x8*)&Alo[r * 40 + l4 * 8];
        }
        #pragma unroll
        for (int jb = 0; jb < 2; ++jb){
            int c = wv * 32 + jb * 16 + l15;
            bh[jb] = *(const bf16x8*)&Bhi[c * 40 + l4 * 8];
            bl[jb] = *(const bf16x8*)&Blo[c * 40 + l4 * 8];
        }
        #pragma unroll
        for (int ib = 0; ib < 4; ++ib)
            #pragma unroll
            for (int jb = 0; jb < 2; ++jb){
                acc[ib][jb] = __builtin_amdgcn_mfma_f32_16x16x32_bf16(ah[ib], bh[jb], acc[ib][jb], 0, 0, 0);
                acc[ib][jb] = __builtin_amdgcn_mfma_f32_16x16x32_bf16(ah[ib], bl[jb], acc[ib][jb], 0, 0, 0);
                acc[ib][jb] = __builtin_amdgcn_mfma_f32_16x16x32_bf16(al[ib], bh[jb], acc[ib][jb], 0, 0, 0);
            }
        __syncthreads();
    }

    // spill S tile to LDS: C/D layout col=lane&15, row=(lane>>4)*4+reg  [m89]
    #pragma unroll
    for (int ib = 0; ib < 4; ++ib)
        #pragma unroll
        for (int jb = 0; jb < 2; ++jb)
            #pragma unroll
            for (int r = 0; r < 4; ++r)
                S[(ib * 16 + l4 * 4 + r) * 129 + wv * 32 + jb * 16 + l15] = acc[ib][jb][r];
    __syncthreads();

    // per-row scan (j ascending => numpy first-occurrence tie rule)
    int row = tid >> 2, seg = (tid & 3) * 32;
    float m1 = -1e30f, m2 = -1e30f; int j1 = -1;
    for (int q = 0; q < 32; ++q){
        float v = S[row * 129 + seg + q];
        if (v > m1){ m2 = m1; m1 = v; j1 = jt * 128 + seg + q; }
        else if (v > m2) m2 = v;
    }
    cm1[row * 4 + (tid & 3)] = m1;
    cm2[row * 4 + (tid & 3)] = m2;
    cj1[row * 4 + (tid & 3)] = j1;
    __syncthreads();
    if (tid < 64){
        float M1 = -1e30f, M2 = -1e30f; int J1 = -1;
        #pragma unroll
        for (int s2 = 0; s2 < 4; ++s2){  // ascending j segments: strict > keeps lowest j
            float a1 = cm1[tid * 4 + s2], a2 = cm2[tid * 4 + s2]; int aj = cj1[tid * 4 + s2];
            if (a1 > M1){ M2 = fmaxf(M1, a2); M1 = a1; J1 = aj; }
            else M2 = fmaxf(M2, a1);
        }
        long idx = ((long)b * T_ + it * 64 + tid) * 4 + jt;
        pmax1[idx] = M1; pmax2[idx] = M2; pj1[idx] = J1;
    }
}

// ---------------- reduce partials, flag borderline rows ----------------
__global__ __launch_bounds__(256) void reduce_k(const float* __restrict__ pmax1,
                                                const int*   __restrict__ pj1,
                                                const float* __restrict__ pmax2,
                                                int* __restrict__ node_idx,
                                                int* __restrict__ flagcnt,
                                                int* __restrict__ flaglist){
    int t = blockIdx.x * 256 + threadIdx.x;
    if (t >= B_ * T_) return;
    float M1 = -1e30f, M2 = -1e30f; int J1 = -1;
    #pragma unroll
    for (int jt = 0; jt < 4; ++jt){   // ascending jt: lowest-j tie rule preserved
        float a1 = pmax1[(long)t * 4 + jt], a2 = pmax2[(long)t * 4 + jt];
        int aj = pj1[(long)t * 4 + jt];
        if (a1 > M1){ M2 = fmaxf(M1, a2); M1 = a1; J1 = aj; }
        else M2 = fmaxf(M2, a1);
    }
    node_idx[t] = J1;
    int i = t & (T_ - 1);
    if (i != 0 && (M1 - M2) < TAU){
        int p = atomicAdd(flagcnt, 1);
        flaglist[p] = t;
    }
}

// ---------------- fp64 exact rescore of flagged rows ----------------
__global__ __launch_bounds__(256) void exact_k(const float* __restrict__ hs,
                                               const double* __restrict__ nsq,
                                               const int* __restrict__ flagcnt,
                                               const int* __restrict__ flaglist,
                                               int* __restrict__ node_idx){
    __shared__ float arow[D_];
    __shared__ double wbv[4];
    __shared__ int wbj[4];
    int nf = *flagcnt;
    for (int f = blockIdx.x; f < nf; f += gridDim.x){
        __syncthreads();
        int t = flaglist[f];
        int b = t >> 9, i = t & 511;
        for (int d = threadIdx.x; d < D_; d += 256)
            arow[d] = hs[((long)b * L_ + 2 * i) * D_ + d];
        __syncthreads();
        int wv = threadIdx.x >> 6, lane = threadIdx.x & 63;
        double bv = -1e300; int bj = -1;
        for (int j = wv; j < T_; j += 4){
            const float* brow = hs + ((long)b * L_ + 2 * j + 1) * D_;
            double s = 0.0;
            #pragma unroll
            for (int dd = 0; dd < 12; ++dd){
                int d = dd * 64 + lane;
                s += (double)arow[d] * (double)brow[d];
            }
            #pragma unroll
            for (int off = 32; off; off >>= 1) s += __shfl_xor(s, off);
            double sc = s / sqrt(nsq[(long)b * L_ + 2 * j + 1]); // row-uniform 1/|a_i| dropped
            if (sc > bv){ bv = sc; bj = j; }
        }
        if (lane == 0){ wbv[wv] = bv; wbj[wv] = bj; }
        __syncthreads();
        if (threadIdx.x == 0){
            double BV = -1e300; int BJ = 1 << 30;
            #pragma unroll
            for (int w2 = 0; w2 < 4; ++w2)
                if (wbv[w2] > BV || (wbv[w2] == BV && wbj[w2] < BJ)){ BV = wbv[w2]; BJ = wbj[w2]; }
            node_idx[t] = BJ;
        }
        __syncthreads();
    }
}

// ---------------- deterministic CSR (stable by source index) ----------------
__global__ __launch_bounds__(512) void csr_k(const int* __restrict__ node_idx,
                                             int* __restrict__ goff,
                                             int* __restrict__ glist){
    __shared__ int sidx[512];
    __shared__ int off[513];
    __shared__ int tmp[512];
    int b = blockIdx.x, t = threadIdx.x;
    sidx[t] = node_idx[b * T_ + t];
    __shared__ int cnt[512];
    cnt[t] = 0;
    __syncthreads();
    if (t >= 1) atomicAdd(&cnt[sidx[t]], 1);   // i=0 excluded (always unmerged)
    __syncthreads();
    tmp[t] = cnt[t];
    __syncthreads();
    for (int s = 1; s < 512; s <<= 1){
        int v = (t >= s) ? tmp[t - s] : 0;
        __syncthreads();
        tmp[t] += v;
        __syncthreads();
    }
    if (t == 0) off[0] = 0;
    off[t + 1] = tmp[t];
    __syncthreads();
    if (t >= 1){
        int j = sidx[t], r = 0;
        for (int i2 = 1; i2 < t; ++i2) r += (sidx[i2] == j);  // stable rank
        glist[b * T_ + off[j] + r] = t;
    }
    goff[b * 513 + t] = off[t];
    if (t == 0) goff[b * 513 + 512] = off[512];
}

// ---------------- merge: gather sources per dst, mean, write ----------------
__global__ __launch_bounds__(256) void merge_k(const float* __restrict__ hs,
                                               const int* __restrict__ goff,
                                               const int* __restrict__ glist,
                                               float* __restrict__ out){
    int bid = blockIdx.x;
    int b = bid / DT_, jj = bid - b * DT_;
    long obase = ((long)b * DT_ + jj) * D_;
    int d0 = threadIdx.x, d1 = d0 + 256, d2 = d0 + 512;
    if (jj == 0){  // unmerged token = src[0] = seq 0
        const float* src = hs + (long)b * L_ * D_;
        out[obase + d0] = src[d0]; out[obase + d1] = src[d1]; out[obase + d2] = src[d2];
        return;
    }
    int j = jj - 1;
    int o0 = goff[b * 513 + j], o1 = goff[b * 513 + j + 1];
    const float* dst = hs + ((long)b * L_ + 2 * j + 1) * D_;
    float a0 = dst[d0], a1 = dst[d1], a2 = dst[d2];
    for (int s = o0; s < o1; ++s){   // ascending source index: deterministic
        int i = glist[b * T_ + s];
        const float* srow = hs + ((long)b * L_ + 2 * i) * D_;
        a0 += srow[d0]; a1 += srow[d1]; a2 += srow[d2];
    }
    float cnt = (float)(o1 - o0 + 1);
    out[obase + d0] = a0 / cnt;
    out[obase + d1] = a1 / cnt;
    out[obase + d2] = a2 / cnt;
}

__global__ __launch_bounds__(256) void mask_k(float* __restrict__ out){
    int t = blockIdx.x * 256 + threadIdx.x;
    if (t < B_ * DT_) out[(long)B_ * DT_ * D_ + t] = 0.0f;
}

extern "C" void kernel_launch(void* const* d_in, const int* in_sizes, int n_in,
                              void* d_out, int out_size, void* d_ws, size_t ws_size,
                              hipStream_t stream){
    const float* hs = (const float*)d_in[0];  // (128,1024,768) f32
    float* out = (float*)d_out;
    char* ws = (char*)d_ws;

    float*  rnorm    = (float*) (ws + 0);         // 524288 B
    double* nsq      = (double*)(ws + 524288);    // 1048576 B
    float*  pmax1    = (float*) (ws + 1572864);   // 1048576 B
    int*    pj1      = (int*)   (ws + 2621440);   // 1048576 B
    float*  pmax2    = (float*) (ws + 3670016);   // 1048576 B
    int*    node_idx = (int*)   (ws + 4718592);   // 262144 B
    int*    flagcnt  = (int*)   (ws + 4980736);   // 256 B
    int*    flaglist = (int*)   (ws + 4980992);   // 262144 B
    int*    goff     = (int*)   (ws + 5243136);   // 263168 B
    int*    glist    = (int*)   (ws + 5506304);   // 262144 B  -> total ~5.77 MB

    hipMemsetAsync(flagcnt, 0, 4, stream);
    norms_k <<<B_ * L_ / 4, 256, 0, stream>>>(hs, rnorm, nsq);
    scores_k<<<B_ * 32,     256, 0, stream>>>(hs, rnorm, pmax1, pj1, pmax2);
    reduce_k<<<B_ * T_ / 256, 256, 0, stream>>>(pmax1, pj1, pmax2, node_idx, flagcnt, flaglist);
    exact_k <<<256,         256, 0, stream>>>(hs, nsq, flagcnt, flaglist, node_idx);
    csr_k   <<<B_,          512, 0, stream>>>(node_idx, goff, glist);
    merge_k <<<B_ * DT_,    256, 0, stream>>>(hs, goff, glist, out);
    mask_k  <<<(B_ * DT_ + 255) / 256, 256, 0, stream>>>(out);
}